// Round 11
// baseline (585.177 us; speedup 1.0000x reference)
//
#include <hip/hip_runtime.h>

#define THRESH 0.1f

typedef float    f4 __attribute__((ext_vector_type(4)));
typedef float    f2 __attribute__((ext_vector_type(2)));
typedef _Float16 h8 __attribute__((ext_vector_type(8)));
typedef _Float16 h4 __attribute__((ext_vector_type(4)));
typedef _Float16 h2 __attribute__((ext_vector_type(2)));

// ---------------------------------------------------------------------------
// Merged weight norm (per-row reduction math identical to all prior rounds).
// Linear rows written PERMUTED to HWC fanin order (values unchanged).
// ---------------------------------------------------------------------------
__global__ void wnorm_all(const float* __restrict__ c0v, const float* __restrict__ c0g,
                          const float* __restrict__ c1v, const float* __restrict__ c1g,
                          const float* __restrict__ c2v, const float* __restrict__ c2g,
                          const float* __restrict__ c3v, const float* __restrict__ c3g,
                          const float* __restrict__ lv,  const float* __restrict__ lg,
                          float* __restrict__ w0, float* __restrict__ w1,
                          float* __restrict__ w2, float* __restrict__ w3,
                          float* __restrict__ wl) {
    int rb = blockIdx.x;
    const float *v, *g; float* w; int fanin, row;
    if (rb < 8)        { v = c0v; g = c0g; w = w0; fanin = 18;   row = rb; }
    else if (rb < 24)  { v = c1v; g = c1g; w = w1; fanin = 72;   row = rb - 8; }
    else if (rb < 56)  { v = c2v; g = c2g; w = w2; fanin = 144;  row = rb - 24; }
    else if (rb < 120) { v = c3v; g = c3g; w = w3; fanin = 288;  row = rb - 56; }
    else               { v = lv;  g = lg;  w = wl; fanin = 1024; row = rb - 120; }
    const bool perm = (rb >= 120);

    const float* vr = v + (size_t)row * fanin;
    float ss = 0.f;
    for (int i = threadIdx.x; i < fanin; i += 64) { float x = vr[i]; ss = fmaf(x, x, ss); }
    #pragma unroll
    for (int off = 32; off > 0; off >>= 1) ss += __shfl_down(ss, off);
    ss = __shfl(ss, 0);
    float scale = g[row] / sqrtf(ss);
    float* wr = w + (size_t)row * fanin;
    for (int i = threadIdx.x; i < fanin; i += 64) {
        int d = perm ? (((i & 15) << 6) | (i >> 4)) : i;
        wr[d] = vr[i] * scale;
    }
}

// ---------------------------------------------------------------------------
// Fused conv3x3(SAME) + IAF + 2x2 avgpool — WAVE-PRIVATE, BARRIER-FREE.
// One 64-thread block = one wave = WY rows x WX cols of conv pixels x CG couts.
// The wave stages its own strip (+halo) slab (double-buffered) and reads only
// its own writes -> same-wave DS program ordering, zero __syncthreads.
// Inter-layer tensors: f16 HWC (exact spike averages -> (float)h bit-exact).
// LDS: [row][col][c], PSB bytes/position (odd-quad 16B-mult for HIN layers).
// Pipeline per t: stage(t+1) -> gather(t+2) -> compute t -> spike/pool/store.
// fmaf chain (ci asc, k asc), staged values, pool assoc identical to r3-r10
// -> bitwise-identical output. L0: f32 planar input, f2 staging, WREG weights.
// ---------------------------------------------------------------------------
template<int CIN, int H, int COUT, int CG, int WX, int PSB>
__launch_bounds__(64, 4)
__global__ void conv_iaf_pool(const void* __restrict__ in_, const float* __restrict__ w,
                              _Float16* __restrict__ out, int B, int T) {
    constexpr bool HIN  = (CIN % 8 == 0);
    constexpr int Hp    = H / 2;
    constexpr int PP    = Hp * Hp;
    constexpr int HH    = H * H;
    constexpr int WY    = 64 / WX;           // conv rows per wave
    constexpr int XW    = H / WX;            // waves across x (L0: 2, else 1)
    constexpr int STRIPS= H / WY;
    constexpr int CGRP  = COUT / CG;
    constexpr int SR    = WY + 2;            // staged rows (with halo)
    constexpr int COLS  = (XW == 1) ? (H + 2) : (WX + 2);   // staged cols
    constexpr int SLABB = SR * COLS * PSB;
    constexpr bool FULLY= (WY == H);         // L3: wave covers whole frame
    constexpr int R0    = FULLY ? 1 : 0;
    constexpr int NRR   = FULLY ? H : SR;    // staged-row iterations
    constexpr int SCN   = (XW == 1) ? H : (WX + 2);  // staged-col iterations
    constexpr int UPC   = HIN ? (CIN / 8) : 1;       // units per position
    constexpr int NU    = NRR * SCN * UPC;
    constexpr int UN    = (NU + 63) / 64;
    constexpr bool GUARD= !(FULLY && (NU % 64 == 0));

    __shared__ alignas(16) char slab[2][SLABB];

    const int l = threadIdx.x;
    const int G = gridDim.x, bx = blockIdx.x;
    const int p = (bx & 7) * (G >> 3) + (bx >> 3);   // XCD clustering: same-b together

    const int cgb   = p % CGRP;
    const int r1    = p / CGRP;
    const int strip = r1 % STRIPS;
    const int r2    = r1 / STRIPS;
    const int xw    = r2 % XW;
    const int b     = r2 / XW;

    const int xl = l % WX, ylw = l / WX;
    const int x0 = xw * WX, y0 = strip * WY;
    const int x  = x0 + xl, y = y0 + ylw;

    const int c0 = cgb * CG;                 // wave-uniform
    const float* __restrict__ wu = w + (size_t)c0 * (CIN * 9);

    // patch base byte offsets (staged row ylw+dr, staged col xl+dc)
    int addrB[9];
    #pragma unroll
    for (int dr = 0; dr < 3; ++dr)
        #pragma unroll
        for (int dc = 0; dc < 3; ++dc)
            addrB[dr * 3 + dc] = ((ylw + dr) * COLS + (xl + dc)) * PSB;

    // staging maps (lane-invariant over t)
    int goff[UN], loffB[UN];
    #pragma unroll
    for (int i = 0; i < UN; ++i) {
        const int idx = l + i * 64;
        int j, jx, ridx;
        if constexpr (HIN) { j = idx % UPC; jx = (idx / UPC) % SCN; ridx = idx / (UPC * SCN); }
        else               { j = 0;         jx = idx % SCN;         ridx = idx / SCN; }
        const int rr = R0 + ridx;
        const int gy = y0 - 1 + rr;
        const int gx = (XW == 1) ? jx : (x0 - 1 + jx);
        const int sc = (XW == 1) ? (jx + 1) : jx;
        const bool ok = (idx < NU) && ((unsigned)gy < (unsigned)H) &&
                        ((unsigned)gx < (unsigned)H);
        if constexpr (HIN) goff[i] = ok ? ((gy * H + gx) * UPC + j) : -1;
        else               goff[i] = ok ? (gy * H + gx) : -1;
        loffB[i] = ok ? ((rr * COLS + sc) * PSB + 16 * j) : -1;
    }

    constexpr bool WREG = !HIN && (CG * CIN * 9) <= 80;   // L0 only
    float wreg[WREG ? (CG * CIN * 9) : 1];
    if constexpr (WREG) {
        #pragma unroll
        for (int i = 0; i < CG * CIN * 9; ++i) wreg[i] = wu[i];
    }

    // zero both slabs (halo cells persist as zeros; wave-private -> no sync)
    for (int i = l; i < (2 * SLABB) / 4; i += 64) ((int*)slab)[i] = 0;

    float vmem[CG];
    #pragma unroll
    for (int c = 0; c < CG; ++c) vmem[c] = 0.f;

    f4 pf[UN];
    #define GATHER(t_)                                                            \
        if constexpr (HIN) {                                                      \
            const f4* inb = (const f4*)in_ + (size_t)(b * T + (t_)) * (HH * UPC); \
            _Pragma("unroll")                                                     \
            for (int i = 0; i < UN; ++i) {                                        \
                f4 r_ = {0.f, 0.f, 0.f, 0.f};                                     \
                if (!GUARD || goff[i] >= 0) r_ = inb[goff[i]];                    \
                pf[i] = r_;                                                       \
            }                                                                     \
        } else {                                                                  \
            const float* inb = (const float*)in_ + (size_t)(b * T + (t_)) * (CIN * HH); \
            _Pragma("unroll")                                                     \
            for (int i = 0; i < UN; ++i) {                                        \
                f4 r_ = {0.f, 0.f, 0.f, 0.f};                                     \
                if (goff[i] >= 0) { r_.x = inb[goff[i]]; r_.y = inb[goff[i] + HH]; } \
                pf[i] = r_;                                                       \
            }                                                                     \
        }
    #define STAGE(buf)                                                            \
        _Pragma("unroll")                                                         \
        for (int i = 0; i < UN; ++i) {                                            \
            if (!GUARD || loffB[i] >= 0) {                                        \
                if constexpr (HIN) *(f4*)(&slab[buf][loffB[i]]) = pf[i];          \
                else { f2 v2_; v2_.x = pf[i].x; v2_.y = pf[i].y;                  \
                       *(f2*)(&slab[buf][loffB[i]]) = v2_; }                      \
            }                                                                     \
        }

    {   // prologue: stage frame 0, prefetch frame 1 (no sync — wave-private)
        GATHER(0)
        STAGE(0)
        GATHER(1)
    }

    for (int t = 0; t < T; ++t) {
        if (t + 1 < T) { STAGE((t + 1) & 1) }
        if (t + 2 < T) { GATHER(t + 2) }

        const char* sb = slab[t & 1];
        float acc[CG];
        #pragma unroll
        for (int c = 0; c < CG; ++c) acc[c] = 0.f;

        if constexpr (HIN) {
            #pragma unroll
            for (int o = 0; o < CIN / 8; ++o) {
                h8 P[9];
                #pragma unroll
                for (int k = 0; k < 9; ++k)
                    P[k] = *(const h8*)(sb + addrB[k] + 16 * o);
                #pragma unroll
                for (int cid = 0; cid < 8; ++cid) {
                    const int ci = 8 * o + cid;
                    #pragma unroll
                    for (int c = 0; c < CG; ++c)
                        #pragma unroll
                        for (int k = 0; k < 9; ++k)
                            acc[c] = fmaf((float)P[k][cid],
                                          wu[(size_t)(c * CIN + ci) * 9 + k], acc[c]);
                }
            }
        } else {
            f2 P[9];
            #pragma unroll
            for (int k = 0; k < 9; ++k)
                P[k] = *(const f2*)(sb + addrB[k]);
            #pragma unroll
            for (int cid = 0; cid < 2; ++cid)
                #pragma unroll
                for (int c = 0; c < CG; ++c)
                    #pragma unroll
                    for (int k = 0; k < 9; ++k)
                        acc[c] = fmaf(P[k][cid],
                                      WREG ? wreg[(c * CIN + cid) * 9 + k]
                                           : wu[(size_t)(c * CIN + cid) * 9 + k],
                                      acc[c]);
        }

        float sv[CG];
        #pragma unroll
        for (int c = 0; c < CG; ++c) {
            vmem[c] += acc[c];
            float s = (vmem[c] >= THRESH) ? 1.f : 0.f;
            vmem[c] -= THRESH * s;
            float sum = s;                         // exact 0/1 sums
            sum += __shfl_xor(sum, 1);             // (s0+s1)
            sum += __shfl_xor(sum, WX);            // + (s2+s3)
            sv[c] = 0.25f * sum;                   // {0,.25,.5,.75,1} — exact f16
        }
        if (((xl | ylw) & 1) == 0) {
            const size_t ob = ((size_t)(b * T + t) * PP + (y >> 1) * Hp + (x >> 1)) * COUT + c0;
            if constexpr (CG == 4) {
                h4 hv = {(_Float16)sv[0], (_Float16)sv[1], (_Float16)sv[2], (_Float16)sv[3]};
                *(h4*)(out + ob) = hv;
            } else if constexpr (CG == 2) {
                h2 hv = {(_Float16)sv[0], (_Float16)sv[1]};
                *(h2*)(out + ob) = hv;
            } else {
                out[ob] = (_Float16)sv[0];
            }
        }
    }
    #undef GATHER
    #undef STAGE
}

// ---------------------------------------------------------------------------
// Linear: out (1600, 11) = h (1600, 1024 f16 HWC) @ wl_perm^T (11, 1024)
// ---------------------------------------------------------------------------
__global__ void linear_kernel(const _Float16* __restrict__ h, const float* __restrict__ w,
                              float* __restrict__ out) {
    __shared__ float hs[1024];
    __shared__ float part[16][17];
    const int n = blockIdx.x;
    for (int i = threadIdx.x; i < 1024; i += blockDim.x)
        hs[i] = (float)h[(size_t)n * 1024 + i];
    __syncthreads();
    const int j = threadIdx.x & 15, ch = threadIdx.x >> 4;
    float acc = 0.f;
    if (j < 11) {
        const float* wr = w + (size_t)j * 1024 + ch * 64;
        const float* hh = hs + ch * 64;
        #pragma unroll 8
        for (int k = 0; k < 64; ++k) acc = fmaf(hh[k], wr[k], acc);
    }
    part[j][ch] = acc;
    __syncthreads();
    if (threadIdx.x < 11) {
        float s = 0.f;
        #pragma unroll
        for (int cc = 0; cc < 16; ++cc) s += part[threadIdx.x][cc];
        out[(size_t)n * 11 + threadIdx.x] = s;
    }
}

// ---------------------------------------------------------------------------
extern "C" void kernel_launch(void* const* d_in, const int* in_sizes, int n_in,
                              void* d_out, int out_size, void* d_ws, size_t ws_size,
                              hipStream_t stream) {
    const int B = 32, T = 50;

    const float* x   = (const float*)d_in[0];
    const float* c0v = (const float*)d_in[1];
    const float* c0g = (const float*)d_in[2];
    const float* c1v = (const float*)d_in[3];
    const float* c1g = (const float*)d_in[4];
    const float* c2v = (const float*)d_in[5];
    const float* c2g = (const float*)d_in[6];
    const float* c3v = (const float*)d_in[7];
    const float* c3g = (const float*)d_in[8];
    const float* lv  = (const float*)d_in[9];
    const float* lg  = (const float*)d_in[10];
    float* out = (float*)d_out;

    // Workspace layout
    float* ws = (float*)d_ws;
    float* w0 = ws;                    // 8*2*9     = 144
    float* w1 = w0 + 144;              // 16*8*9    = 1152
    float* w2 = w1 + 1152;             // 32*16*9   = 4608
    float* w3 = w2 + 4608;             // 64*32*9   = 18432
    float* wl = w3 + 18432;            // 11*1024   = 11264 (HWC-permuted)
    _Float16* bufA16 = (_Float16*)(ws + 40960);            // L0 out f16 HWC
    _Float16* bufB16 = (_Float16*)(ws + 40960 + 13107200); // L1 out f16 HWC
    // L2 out reuses bufA16; L3 out reuses bufB16.

    wnorm_all<<<131, 64, 0, stream>>>(c0v, c0g, c1v, c1g, c2v, c2g, c3v, c3g,
                                      lv, lg, w0, w1, w2, w3, wl);

    // <CIN,H,COUT,CG,WX,PSB>; 64-thread wave-private blocks, barrier-free.
    // grid = B * CGRP * STRIPS * XW  (>= 2048 waves = >= 8 waves/CU everywhere)
    conv_iaf_pool<2,  64, 8,  4, 32, 8 ><<<4096, 64, 0, stream>>>(x,       w0, bufA16, B, T); // L0
    conv_iaf_pool<8,  32, 16, 4, 32, 16><<<2048, 64, 0, stream>>>(bufA16,  w1, bufB16, B, T); // L1
    conv_iaf_pool<16, 16, 32, 2, 16, 48><<<2048, 64, 0, stream>>>(bufB16,  w2, bufA16, B, T); // L2
    conv_iaf_pool<32, 8,  64, 1, 8,  80><<<2048, 64, 0, stream>>>(bufA16,  w3, bufB16, B, T); // L3

    linear_kernel<<<B * T, 256, 0, stream>>>(bufB16, wl, out);
}